// Round 12
// baseline (224.805 us; speedup 1.0000x reference)
//
#include <hip/hip_runtime.h>
#include <math.h>

typedef unsigned int U32;
typedef unsigned long long U64;

constexpr int N_SP   = 64 * 96 * 96;   // 589824 spatial positions per batch
constexpr int NBATCH = 2;
constexpr int K_TOP  = 2048;
constexpr int NBINS  = 8192;           // top 13 bits of monotonic float
constexpr int CAP    = 8192;           // candidate capacity per batch
constexpr int CAPB   = 64;             // edge-bucket capacity per 32-row block
constexpr float ANCHOR_F = 12.0f;
constexpr float NMS_IOU_F = 0.25f;

// ---- workspace layout (bytes) ----
constexpr size_t OFF_HIST = 0;                           // u32[2][8192]  = 65536
constexpr size_t OFF_CNT  = OFF_HIST + 2 * NBINS * 4;    // u32[2] (+pad)
constexpr size_t OFF_CAND = OFF_CNT + 256;               // u64[2][8192]  = 131072
constexpr size_t OFF_BOX  = OFF_CAND + 2 * CAP * 8;      // f32[2][14][2048] = 229376
constexpr size_t OFF_MASK = OFF_BOX + 2 * 14 * K_TOP * 4;    // u32[2][2048][64] = 1048576
constexpr size_t OFF_DIAG = OFF_MASK + 2 * K_TOP * 64 * 4;   // u32[2][2048] = 16384
constexpr size_t OFF_BCNT = OFF_DIAG + 2 * K_TOP * 4;        // u32[2][64] = 512
constexpr size_t OFF_BKT  = OFF_BCNT + 512;                  // u64[2][64][64] = 65536
// total ~1.56 MB

__device__ __forceinline__ U32 mono_of(float f) {
  U32 u = __float_as_uint(f);
  return (u & 0x80000000u) ? ~u : (u | 0x80000000u);
}
__device__ __forceinline__ float un_mono(U32 m) {
  U32 u = (m & 0x80000000u) ? (m ^ 0x80000000u) : ~m;
  return __uint_as_float(u);
}

// ---------------------------------------------------------------- zero scratch
__global__ void __launch_bounds__(256) k_zero(U32* hist, U32* cnt, U32* bcnt) {
  int g = blockIdx.x * 256 + threadIdx.x;  // 16384 threads
  hist[g] = 0;
  if (g < NBATCH) cnt[g] = 0;
  if (g < 2 * 64) bcnt[g] = 0;
}

// ---------------------------------------------------------------- histogram
__global__ void __launch_bounds__(256) k_hist(const float* __restrict__ scores,
                                              U32* __restrict__ hist) {
  int b = blockIdx.y;
  const float4* s4 = (const float4*)(scores + (size_t)b * N_SP)
                     + (size_t)blockIdx.x * 2048 + threadIdx.x;
  float4 v[8];
#pragma unroll
  for (int e = 0; e < 8; ++e) v[e] = s4[e * 256];
  __shared__ U32 lh[NBINS];
  for (int k = threadIdx.x; k < NBINS; k += 256) lh[k] = 0;
  __syncthreads();
#pragma unroll
  for (int e = 0; e < 8; ++e) {
    atomicAdd(&lh[mono_of(v[e].x) >> 19], 1u);
    atomicAdd(&lh[mono_of(v[e].y) >> 19], 1u);
    atomicAdd(&lh[mono_of(v[e].z) >> 19], 1u);
    atomicAdd(&lh[mono_of(v[e].w) >> 19], 1u);
  }
  __syncthreads();
  U32* gh = hist + (size_t)b * NBINS;
  for (int k = threadIdx.x; k < NBINS; k += 256) {
    U32 c = lh[k];
    if (c) atomicAdd(&gh[k], c);
  }
}

// ---------------------------------------------------------------- collect (threshold inlined)
__global__ void __launch_bounds__(256) k_collect(const float* __restrict__ scores,
                                                 const U32* __restrict__ hist,
                                                 U32* __restrict__ cnt,
                                                 U64* __restrict__ cand) {
  int b = blockIdx.y;
  int tid = threadIdx.x;
  const float4* s4 = (const float4*)(scores + (size_t)b * N_SP)
                     + (size_t)blockIdx.x * 1024 + tid;
  float4 v[4];
#pragma unroll
  for (int e = 0; e < 4; ++e) v[e] = s4[e * 256];

  // ---- inline threshold ----
  __shared__ U32 part[256];
  __shared__ U32 sthr;
  const U32* h = hist + (size_t)b * NBINS;
  {
    int base = NBINS - 32 * (tid + 1);  // chunk tid covers [base, base+32), desc
    U32 s = 0;
    for (int k = 0; k < 32; ++k) s += h[base + k];
    part[tid] = s;
  }
  __syncthreads();
  if (tid == 0) {
    U32 cum = 0, bin = 0;
    for (int c = 0; c < 256; ++c) {
      U32 p = part[c];
      if (cum + p >= (U32)K_TOP) {
        int hb = NBINS - 32 * c - 1;
        for (int k = 0; k < 32; ++k) {
          cum += h[hb - k];
          if (cum >= (U32)K_TOP) { bin = (U32)(hb - k); break; }
        }
        break;
      }
      cum += p;
    }
    sthr = bin;  // keep all elements with bin >= thr
  }
  __syncthreads();
  U32 tb = sthr;

  // ---- filter into LDS, one global fetch-add per block ----
  __shared__ U64 lbuf[4096];   // worst case: every value in block passes
  __shared__ U32 lcnt, lbase;
  if (tid == 0) lcnt = 0;
  __syncthreads();
#pragma unroll
  for (int e = 0; e < 4; ++e) {
    U32 i0 = (blockIdx.x * 1024 + e * 256 + tid) * 4;
    float vv[4] = {v[e].x, v[e].y, v[e].z, v[e].w};
#pragma unroll
    for (int c = 0; c < 4; ++c) {
      U32 m = mono_of(vv[c]);
      if ((m >> 19) >= tb) {
        U32 p = atomicAdd(&lcnt, 1u);
        // key: score (monotonic) desc, then index asc (~idx desc)
        lbuf[p] = ((U64)m << 32) | (U32)(~(i0 + c));
      }
    }
  }
  __syncthreads();
  if (tid == 0 && lcnt) lbase = atomicAdd(&cnt[b], lcnt);
  __syncthreads();
  U32 n = lcnt;
  if (n == 0) return;
  U32 base = lbase;
  U64* cb = cand + (size_t)b * CAP;
  for (U32 k = tid; k < n; k += 256) {
    U32 pos = base + k;
    if (pos < (U32)CAP) cb[pos] = lbuf[k];
  }
}

// ---- exact-match FP from here on: no contraction (numpy does unfused mul/add)
#pragma clang fp contract(off)

// ---------------------------------------------------------------- sort + gather fused (v3)
// r11 post-mortem: readlane-broadcast rank scan is VALU->SGPR->VALU hazard-
// bound (~17 cyc/value, VALUBusy 2.6%). v3 drops rank-by-comparison entirely:
// one 1024-thread block per batch bitonic-sorts all candidates DESCENDING in
// LDS (O(C log^2 C) ~= 0.7M compare-exchanges vs 7M compares; plain ds ops,
// no cross-lane hazards, 16 waves of TLP), then sorted position == rank.
// Padding key 0 sorts last (real keys always nonzero: low word = ~idx != 0).
// Keys unique (distinct idx) -> identical semantics to rank = #{key_j > key}.
__global__ void __launch_bounds__(1024) k_cg(const float* __restrict__ bboxes,
                                             const U64* __restrict__ cand,
                                             const U32* __restrict__ cnt,
                                             float* __restrict__ box) {
  int b = blockIdx.y;
  int tid = threadIdx.x;
  U32 C = cnt[b]; if (C > (U32)CAP) C = CAP;
  const U64* cb = cand + (size_t)b * CAP;
  __shared__ U64 s[CAP];  // 64 KB
  for (int k = tid; k < CAP; k += 1024) s[k] = ((U32)k < C) ? cb[k] : 0ull;
  __syncthreads();
  // bitonic sort, descending. Swap rule: in "up" regions ((i&k)==0) enforce
  // s[i] >= s[l]; else s[i] <= s[l]. Pair-indexed: 4 exchanges/thread/stage.
  for (int k = 2; k <= CAP; k <<= 1) {
    for (int j = k >> 1; j > 0; j >>= 1) {
      for (int p = tid; p < CAP / 2; p += 1024) {
        int i = ((p & ~(j - 1)) << 1) | (p & (j - 1));
        int l = i | j;
        U64 a = s[i], c = s[l];
        bool up = ((i & k) == 0);
        if ((a < c) == up) { s[i] = c; s[l] = a; }
      }
      __syncthreads();
    }
  }
  // s[0..2047] = top-K keys in rank order; gather + deparametrize.
  for (int r = tid; r < K_TOP; r += 1024) {
    U64 key = s[r];
    U32 idx = ~(U32)(key & 0xFFFFFFFFull);
    float sc = un_mono((U32)(key >> 32));
    int d = idx / 9216;
    int rem = idx - d * 9216;
    int h = rem / 96;
    int w = rem - h * 96;
    const float* src = bboxes + (size_t)b * 6 * N_SP + idx;
    float r0 = src[0];
    float r1 = src[(size_t)N_SP];
    float r2 = src[(size_t)2 * N_SP];
    float r3 = src[(size_t)3 * N_SP];
    float r4 = src[(size_t)4 * N_SP];
    float r5 = src[(size_t)5 * N_SP];
    float cz = r0 * ANCHOR_F + ((float)d + 0.5f);
    float cy = r1 * ANCHOR_F + ((float)h + 0.5f);
    float cx = r2 * ANCHOR_F + ((float)w + 0.5f);
    // double-precision exp then round: matches correctly-rounded f32 np.exp
    float sz = (float)exp((double)r3) * ANCHOR_F;
    float sy = (float)exp((double)r4) * ANCHOR_F;
    float sx = (float)exp((double)r5) * ANCHOR_F;
    float* B0 = box + (size_t)b * 14 * K_TOP;
    B0[0 * K_TOP + r] = cz;  B0[1 * K_TOP + r] = cy;  B0[2 * K_TOP + r] = cx;
    B0[3 * K_TOP + r] = sz;  B0[4 * K_TOP + r] = sy;  B0[5 * K_TOP + r] = sx;
    B0[6 * K_TOP + r] = cz - sz * 0.5f;   // c - s/2 (s*0.5 == s/2 exactly)
    B0[7 * K_TOP + r] = cy - sy * 0.5f;
    B0[8 * K_TOP + r] = cx - sx * 0.5f;
    B0[9 * K_TOP + r] = cz + sz * 0.5f;
    B0[10 * K_TOP + r] = cy + sy * 0.5f;
    B0[11 * K_TOP + r] = cx + sx * 0.5f;
    B0[12 * K_TOP + r] = (sz * sy) * sx;  // vol, left-fold like np.prod
    B0[13 * K_TOP + r] = sc;
  }
}

// ---------------------------------------------------------------- IoU -> mask + diag + edges
__global__ void __launch_bounds__(256) k_mask(const float* __restrict__ box,
                                              U32* __restrict__ mask,
                                              U32* __restrict__ diag,
                                              U32* __restrict__ bcnt,
                                              U64* __restrict__ bkt) {
  int b = blockIdx.y;
  int it = blockIdx.x >> 2;   // i-tile of 64 rows
  int jq = blockIdx.x & 3;    // j quarter of 512 cols
  const float* B0 = box + (size_t)b * 14 * K_TOP;
  __shared__ float ls[7][512];  // min0..2, max0..2, vol for the j-quarter
  int j0 = jq * 512;
  for (int k = threadIdx.x; k < 7 * 512; k += 256) {
    int a = k >> 9, j = k & 511;
    ls[a][j] = B0[(size_t)(6 + a) * K_TOP + j0 + j];
  }
  __syncthreads();
  int lane = threadIdx.x & 63;
  int wv = threadIdx.x >> 6;     // wave 0..3 -> 128-col slice
  int i = it * 64 + lane;
  float imin0 = B0[6 * K_TOP + i], imin1 = B0[7 * K_TOP + i], imin2 = B0[8 * K_TOP + i];
  float imax0 = B0[9 * K_TOP + i], imax1 = B0[10 * K_TOP + i], imax2 = B0[11 * K_TOP + i];
  float ivol  = B0[12 * K_TOP + i];
  U32 wbits[4];
  int jb = wv * 128;
#pragma unroll
  for (int wl = 0; wl < 4; ++wl) {
    U32 bits = 0;
    for (int bit = 0; bit < 32; ++bit) {
      int jl = jb + wl * 32 + bit;
      int j = j0 + jl;
      float lo0 = fmaxf(imin0, ls[0][jl]);
      float lo1 = fmaxf(imin1, ls[1][jl]);
      float lo2 = fmaxf(imin2, ls[2][jl]);
      float hi0 = fminf(imax0, ls[3][jl]);
      float hi1 = fminf(imax1, ls[4][jl]);
      float hi2 = fminf(imax2, ls[5][jl]);
      float d0 = fmaxf(hi0 - lo0, 0.0f);
      float d1 = fmaxf(hi1 - lo1, 0.0f);
      float d2 = fmaxf(hi2 - lo2, 0.0f);
      float inter = (d0 * d1) * d2;
      float uni = (ivol + ls[6][jl]) - inter;
      float iou = inter / uni;  // IEEE div, matches reference semantics
      bits |= ((iou > NMS_IOU_F) && (j > i)) ? (1u << bit) : 0u;
    }
    wbits[wl] = bits;
  }
  uint4* mrow = (uint4*)(mask + ((size_t)(b * K_TOP + i)) * 64);
  mrow[jq * 4 + wv] = make_uint4(wbits[0], wbits[1], wbits[2], wbits[3]);
  U32* dgp = diag + (size_t)b * K_TOP;
  int g_src = i >> 5;
  U32* bc = bcnt + b * 64 + g_src;
  U64* bb = bkt + ((size_t)(b * 64 + g_src)) * CAPB;
#pragma unroll
  for (int wl = 0; wl < 4; ++wl) {
    int w = jq * 16 + wv * 4 + wl;
    if (w == (i >> 5)) dgp[i] = wbits[wl];  // exactly one (jq,wv,wl) per row
    if (wbits[wl]) {
      U32 p = atomicAdd(bc, 1u);
      if (p < (U32)CAPB)
        bb[p] = ((U64)((U32)((i & 31) << 6) | (U32)w) << 32) | wbits[wl];
    }
  }
}

// ---------------------------------------------------------------- edge-list greedy NMS + output
__global__ void __launch_bounds__(256) k_nms(const float* __restrict__ box,
                                             const U32* __restrict__ mask,
                                             const U32* __restrict__ diag,
                                             const U32* __restrict__ bcnt,
                                             const U64* __restrict__ bkt,
                                             float* __restrict__ out) {
  int b = blockIdx.x;
  int tid = threadIdx.x;
  int wv = tid >> 6, lane = tid & 63;
  const U32* mk = mask + (size_t)b * K_TOP * 64;
  const U32* dgp = diag + (size_t)b * K_TOP;
  const U32* bcg = bcnt + b * 64;
  const U64* bkg = bkt + (size_t)b * 64 * CAPB;

  __shared__ U64 lbkt[64 * CAPB];    // 32 KB
  __shared__ U32 ldiag[K_TOP];       // 8 KB
  __shared__ U32 lcnt[64];
  __shared__ U32 keepArr[64];

  // flat, fully-overlapped prologue copies — all loads in flight together
  for (int k = tid; k < K_TOP; k += 256) ldiag[k] = dgp[k];
  for (int k = tid; k < 64 * CAPB; k += 256) lbkt[k] = bkg[k];
  if (tid < 64) lcnt[tid] = bcg[tid];
  __syncthreads();

  if (wv == 0) {
    U32 keep = 0xFFFFFFFFu;  // lane l holds keep word l (j in [32l,32l+32))
    U32 cnt_l = lcnt[lane];
    bool ovf = (__ballot(cnt_l > (U32)CAPB) != 0ull);
    if (!ovf) {
      // -------- main path: O(E) --------
      for (int g = 0; g < 64; ++g) {
        U32 kw = (U32)__builtin_amdgcn_readlane((int)keep, g);
        if (!kw) continue;
        U32 dgl = ldiag[g * 32 + (lane & 31)];
        U32 nzw = (U32)__ballot(dgl != 0);   // low 32 = nonzero-diag bitmap
        U32 m = kw & nzw;
        while (m) {  // intra-block resolve: only rows with nonzero diag
          int q = __builtin_ctz(m);
          if ((kw >> q) & 1u)
            kw &= ~(U32)__builtin_amdgcn_readlane((int)dgl, q);
          m &= m - 1;
        }
        U32 n = (U32)__builtin_amdgcn_readlane((int)cnt_l, g);
        U32 acc = 0;
        for (U32 e0 = 0; e0 < n; e0 += 64) {
          U64 ev = lbkt[(U32)g * CAPB + e0 + (U32)lane];
          U32 evLo = (U32)ev, evHi = (U32)(ev >> 32);
          U32 lim = (n - e0 > 64u) ? 64u : (n - e0);
          for (U32 t = 0; t < lim; ++t) {
            U32 hi = (U32)__builtin_amdgcn_readlane((int)evHi, (int)t);
            U32 bt = (U32)__builtin_amdgcn_readlane((int)evLo, (int)t);
            U32 il = (hi >> 6) & 31u, w = hi & 63u;
            if ((kw >> il) & 1u)  // source row final-alive (uniform)
              acc |= (w == (U32)lane) ? bt : 0u;
          }
        }
        keep &= ~acc;  // lane g reproduces kw exactly (j>i diag argument)
      }
    } else {
      // -------- fallback: dense global (correct for any data) --------
      for (int g = 0; g < 64; ++g) {
        U32 kw = (U32)__builtin_amdgcn_readlane((int)keep, g);
        U32 dgl = ldiag[g * 32 + (lane & 31)];
#pragma unroll
        for (int q = 0; q < 32; ++q)
          if ((kw >> q) & 1u)
            kw &= ~(U32)__builtin_amdgcn_readlane((int)dgl, q);
        U32 rw[32];
#pragma unroll
        for (int q = 0; q < 32; ++q)
          rw[q] = mk[(size_t)(g * 32 + q) * 64 + lane];
        U32 acc = 0;
#pragma unroll
        for (int q = 0; q < 32; ++q) acc |= ((kw >> q) & 1u) ? rw[q] : 0u;
        keep &= ~acc;
      }
    }
    keepArr[lane] = keep;
  }
  __syncthreads();

  const float* B0 = box + (size_t)b * 14 * K_TOP;
  for (int t = tid; t < K_TOP; t += 256) {
    U32 kp = (keepArr[t >> 5] >> (t & 31)) & 1u;
    float sc = B0[13 * K_TOP + t];
    float vz = B0[0 * K_TOP + t], vy = B0[1 * K_TOP + t], vx = B0[2 * K_TOP + t];
    float dz = B0[3 * K_TOP + t], dy = B0[4 * K_TOP + t], dx = B0[5 * K_TOP + t];
    float* o = out + (size_t)(b * K_TOP + t) * 7;
    o[0] = kp ? sc : 0.0f;
    o[1] = kp ? vz : 0.0f;
    o[2] = kp ? vy : 0.0f;
    o[3] = kp ? vx : 0.0f;
    o[4] = kp ? dz : 0.0f;
    o[5] = kp ? dy : 0.0f;
    o[6] = kp ? dx : 0.0f;
  }
}

extern "C" void kernel_launch(void* const* d_in, const int* in_sizes, int n_in,
                              void* d_out, int out_size, void* d_ws, size_t ws_size,
                              hipStream_t stream) {
  const float* bboxes = (const float*)d_in[0];  // (2,6,64,96,96) f32
  const float* scores = (const float*)d_in[1];  // (2,64,96,96) f32
  float* out = (float*)d_out;                   // (2,2048,7) f32

  char* ws = (char*)d_ws;
  U32* hist = (U32*)(ws + OFF_HIST);
  U32* cnt  = (U32*)(ws + OFF_CNT);
  U64* cand = (U64*)(ws + OFF_CAND);
  float* box = (float*)(ws + OFF_BOX);
  U32* mask = (U32*)(ws + OFF_MASK);
  U32* diag = (U32*)(ws + OFF_DIAG);
  U32* bcnt = (U32*)(ws + OFF_BCNT);
  U64* bkt  = (U64*)(ws + OFF_BKT);

  k_zero<<<64, 256, 0, stream>>>(hist, cnt, bcnt);
  k_hist<<<dim3(72, NBATCH), 256, 0, stream>>>(scores, hist);
  k_collect<<<dim3(144, NBATCH), 256, 0, stream>>>(scores, hist, cnt, cand);
  k_cg<<<dim3(1, NBATCH), 1024, 0, stream>>>(bboxes, cand, cnt, box);
  k_mask<<<dim3(128, NBATCH), 256, 0, stream>>>(box, mask, diag, bcnt, bkt);
  k_nms<<<NBATCH, 256, 0, stream>>>(box, mask, diag, bcnt, bkt, out);
}

// Round 13
// 175.844 us; speedup vs baseline: 1.2784x; 1.2784x over previous
//
#include <hip/hip_runtime.h>
#include <math.h>

typedef unsigned int U32;
typedef unsigned long long U64;

constexpr int N_SP   = 64 * 96 * 96;   // 589824 spatial positions per batch
constexpr int NBATCH = 2;
constexpr int K_TOP  = 2048;
constexpr int NBINS  = 8192;           // top 13 bits of monotonic float
constexpr int CAP    = 8192;           // candidate capacity per batch
constexpr int CAPB   = 64;             // edge-bucket capacity per 32-row block
constexpr float ANCHOR_F = 12.0f;
constexpr float NMS_IOU_F = 0.25f;

// ---- workspace layout (bytes) ----
constexpr size_t OFF_HIST = 0;                           // u32[2][8192]  = 65536
constexpr size_t OFF_CNT  = OFF_HIST + 2 * NBINS * 4;    // u32[2] (+pad)
constexpr size_t OFF_CAND = OFF_CNT + 256;               // u64[2][8192]  = 131072
constexpr size_t OFF_BOX  = OFF_CAND + 2 * CAP * 8;      // f32[2][14][2048] = 229376
constexpr size_t OFF_MASK = OFF_BOX + 2 * 14 * K_TOP * 4;    // u32[2][2048][64] = 1048576
constexpr size_t OFF_DIAG = OFF_MASK + 2 * K_TOP * 64 * 4;   // u32[2][2048] = 16384
constexpr size_t OFF_BCNT = OFF_DIAG + 2 * K_TOP * 4;        // u32[2][64] = 512
constexpr size_t OFF_BKT  = OFF_BCNT + 512;                  // u64[2][64][64] = 65536
// total ~1.56 MB

__device__ __forceinline__ U32 mono_of(float f) {
  U32 u = __float_as_uint(f);
  return (u & 0x80000000u) ? ~u : (u | 0x80000000u);
}
__device__ __forceinline__ float un_mono(U32 m) {
  U32 u = (m & 0x80000000u) ? (m ^ 0x80000000u) : ~m;
  return __uint_as_float(u);
}

// ---------------------------------------------------------------- zero scratch
__global__ void __launch_bounds__(256) k_zero(U32* hist, U32* cnt, U32* bcnt) {
  int g = blockIdx.x * 256 + threadIdx.x;  // 16384 threads
  hist[g] = 0;
  if (g < NBATCH) cnt[g] = 0;
  if (g < 2 * 64) bcnt[g] = 0;
}

// ---------------------------------------------------------------- histogram
__global__ void __launch_bounds__(256) k_hist(const float* __restrict__ scores,
                                              U32* __restrict__ hist) {
  int b = blockIdx.y;
  const float4* s4 = (const float4*)(scores + (size_t)b * N_SP)
                     + (size_t)blockIdx.x * 2048 + threadIdx.x;
  float4 v[8];
#pragma unroll
  for (int e = 0; e < 8; ++e) v[e] = s4[e * 256];
  __shared__ U32 lh[NBINS];
  for (int k = threadIdx.x; k < NBINS; k += 256) lh[k] = 0;
  __syncthreads();
#pragma unroll
  for (int e = 0; e < 8; ++e) {
    atomicAdd(&lh[mono_of(v[e].x) >> 19], 1u);
    atomicAdd(&lh[mono_of(v[e].y) >> 19], 1u);
    atomicAdd(&lh[mono_of(v[e].z) >> 19], 1u);
    atomicAdd(&lh[mono_of(v[e].w) >> 19], 1u);
  }
  __syncthreads();
  U32* gh = hist + (size_t)b * NBINS;
  for (int k = threadIdx.x; k < NBINS; k += 256) {
    U32 c = lh[k];
    if (c) atomicAdd(&gh[k], c);
  }
}

// ---------------------------------------------------------------- collect (threshold inlined)
__global__ void __launch_bounds__(256) k_collect(const float* __restrict__ scores,
                                                 const U32* __restrict__ hist,
                                                 U32* __restrict__ cnt,
                                                 U64* __restrict__ cand) {
  int b = blockIdx.y;
  int tid = threadIdx.x;
  const float4* s4 = (const float4*)(scores + (size_t)b * N_SP)
                     + (size_t)blockIdx.x * 1024 + tid;
  float4 v[4];
#pragma unroll
  for (int e = 0; e < 4; ++e) v[e] = s4[e * 256];

  // ---- inline threshold ----
  __shared__ U32 part[256];
  __shared__ U32 sthr;
  const U32* h = hist + (size_t)b * NBINS;
  {
    int base = NBINS - 32 * (tid + 1);  // chunk tid covers [base, base+32), desc
    U32 s = 0;
    for (int k = 0; k < 32; ++k) s += h[base + k];
    part[tid] = s;
  }
  __syncthreads();
  if (tid == 0) {
    U32 cum = 0, bin = 0;
    for (int c = 0; c < 256; ++c) {
      U32 p = part[c];
      if (cum + p >= (U32)K_TOP) {
        int hb = NBINS - 32 * c - 1;
        for (int k = 0; k < 32; ++k) {
          cum += h[hb - k];
          if (cum >= (U32)K_TOP) { bin = (U32)(hb - k); break; }
        }
        break;
      }
      cum += p;
    }
    sthr = bin;  // keep all elements with bin >= thr
  }
  __syncthreads();
  U32 tb = sthr;

  // ---- filter into LDS, one global fetch-add per block ----
  __shared__ U64 lbuf[4096];   // worst case: every value in block passes
  __shared__ U32 lcnt, lbase;
  if (tid == 0) lcnt = 0;
  __syncthreads();
#pragma unroll
  for (int e = 0; e < 4; ++e) {
    U32 i0 = (blockIdx.x * 1024 + e * 256 + tid) * 4;
    float vv[4] = {v[e].x, v[e].y, v[e].z, v[e].w};
#pragma unroll
    for (int c = 0; c < 4; ++c) {
      U32 m = mono_of(vv[c]);
      if ((m >> 19) >= tb) {
        U32 p = atomicAdd(&lcnt, 1u);
        // key: score (monotonic) desc, then index asc (~idx desc)
        lbuf[p] = ((U64)m << 32) | (U32)(~(i0 + c));
      }
    }
  }
  __syncthreads();
  if (tid == 0 && lcnt) lbase = atomicAdd(&cnt[b], lcnt);
  __syncthreads();
  U32 n = lcnt;
  if (n == 0) return;
  U32 base = lbase;
  U64* cb = cand + (size_t)b * CAP;
  for (U32 k = tid; k < n; k += 256) {
    U32 pos = base + k;
    if (pos < (U32)CAP) cb[pos] = lbuf[k];
  }
}

// ---- exact-match FP from here on: no contraction (numpy does unfused mul/add)
#pragma clang fp contract(off)

// ---------------------------------------------------------------- rank + gather fused (v4)
// Scorecard: r10 uniform-GLOBAL scan 168us (latency chain); r11 readlane
// broadcast 45us (VALU->SGPR hazard, 1 wave/CU); r12 bitonic 95us (91 barriers
// x 2 blocks). v4: stage candidates into LDS once (coalesced), then rank scan
// reads LDS with UNIFORM address -> broadcast, no bank conflicts, no SGPR
// hazard, no barrier in the loop; unroll-16 keeps 16 independent ds_reads in
// flight. rank = #{j<C: s[j] > kv} — semantics identical to r8's k_count
// (keys unique; sentinel 0 loses to all real keys; C >= K_TOP by threshold
// construction so all 2048 output rows are written).
__global__ void __launch_bounds__(256) k_cg(const float* __restrict__ bboxes,
                                            const U64* __restrict__ cand,
                                            const U32* __restrict__ cnt,
                                            float* __restrict__ box) {
  int b = blockIdx.y;
  int tid = threadIdx.x;
  U32 C = cnt[b]; if (C > (U32)CAP) C = CAP;
  if ((U32)(blockIdx.x * 256) >= C) return;  // whole block past candidates
  const U64* cb = cand + (size_t)b * CAP;
  __shared__ U64 s[CAP];  // 64 KB
  for (U32 k = tid; k < C; k += 256) s[k] = cb[k];
  __syncthreads();
  U32 t = (U32)(blockIdx.x * 256 + tid);
  U64 kv = (t < C) ? s[t] : 0ull;
  U32 rk = 0;
#pragma unroll 16
  for (U32 j = 0; j < C; ++j) rk += (s[j] > kv) ? 1u : 0u;
  if (t >= C || rk >= (U32)K_TOP) return;
  U32 r = rk;
  U64 key = kv;
  U32 idx = ~(U32)(key & 0xFFFFFFFFull);
  float sc = un_mono((U32)(key >> 32));
  int d = idx / 9216;
  int rem = idx - d * 9216;
  int h = rem / 96;
  int w = rem - h * 96;
  const float* src = bboxes + (size_t)b * 6 * N_SP + idx;
  float r0 = src[0];
  float r1 = src[(size_t)N_SP];
  float r2 = src[(size_t)2 * N_SP];
  float r3 = src[(size_t)3 * N_SP];
  float r4 = src[(size_t)4 * N_SP];
  float r5 = src[(size_t)5 * N_SP];
  float cz = r0 * ANCHOR_F + ((float)d + 0.5f);
  float cy = r1 * ANCHOR_F + ((float)h + 0.5f);
  float cx = r2 * ANCHOR_F + ((float)w + 0.5f);
  // double-precision exp then round: matches correctly-rounded f32 np.exp
  float sz = (float)exp((double)r3) * ANCHOR_F;
  float sy = (float)exp((double)r4) * ANCHOR_F;
  float sx = (float)exp((double)r5) * ANCHOR_F;
  float* B0 = box + (size_t)b * 14 * K_TOP;
  B0[0 * K_TOP + r] = cz;  B0[1 * K_TOP + r] = cy;  B0[2 * K_TOP + r] = cx;
  B0[3 * K_TOP + r] = sz;  B0[4 * K_TOP + r] = sy;  B0[5 * K_TOP + r] = sx;
  B0[6 * K_TOP + r] = cz - sz * 0.5f;   // c - s/2 (s*0.5 == s/2 exactly)
  B0[7 * K_TOP + r] = cy - sy * 0.5f;
  B0[8 * K_TOP + r] = cx - sx * 0.5f;
  B0[9 * K_TOP + r] = cz + sz * 0.5f;
  B0[10 * K_TOP + r] = cy + sy * 0.5f;
  B0[11 * K_TOP + r] = cx + sx * 0.5f;
  B0[12 * K_TOP + r] = (sz * sy) * sx;  // vol, left-fold like np.prod
  B0[13 * K_TOP + r] = sc;
}

// ---------------------------------------------------------------- IoU -> mask + diag + edges
__global__ void __launch_bounds__(256) k_mask(const float* __restrict__ box,
                                              U32* __restrict__ mask,
                                              U32* __restrict__ diag,
                                              U32* __restrict__ bcnt,
                                              U64* __restrict__ bkt) {
  int b = blockIdx.y;
  int it = blockIdx.x >> 2;   // i-tile of 64 rows
  int jq = blockIdx.x & 3;    // j quarter of 512 cols
  const float* B0 = box + (size_t)b * 14 * K_TOP;
  __shared__ float ls[7][512];  // min0..2, max0..2, vol for the j-quarter
  int j0 = jq * 512;
  for (int k = threadIdx.x; k < 7 * 512; k += 256) {
    int a = k >> 9, j = k & 511;
    ls[a][j] = B0[(size_t)(6 + a) * K_TOP + j0 + j];
  }
  __syncthreads();
  int lane = threadIdx.x & 63;
  int wv = threadIdx.x >> 6;     // wave 0..3 -> 128-col slice
  int i = it * 64 + lane;
  float imin0 = B0[6 * K_TOP + i], imin1 = B0[7 * K_TOP + i], imin2 = B0[8 * K_TOP + i];
  float imax0 = B0[9 * K_TOP + i], imax1 = B0[10 * K_TOP + i], imax2 = B0[11 * K_TOP + i];
  float ivol  = B0[12 * K_TOP + i];
  U32 wbits[4];
  int jb = wv * 128;
#pragma unroll
  for (int wl = 0; wl < 4; ++wl) {
    U32 bits = 0;
    for (int bit = 0; bit < 32; ++bit) {
      int jl = jb + wl * 32 + bit;
      int j = j0 + jl;
      float lo0 = fmaxf(imin0, ls[0][jl]);
      float lo1 = fmaxf(imin1, ls[1][jl]);
      float lo2 = fmaxf(imin2, ls[2][jl]);
      float hi0 = fminf(imax0, ls[3][jl]);
      float hi1 = fminf(imax1, ls[4][jl]);
      float hi2 = fminf(imax2, ls[5][jl]);
      float d0 = fmaxf(hi0 - lo0, 0.0f);
      float d1 = fmaxf(hi1 - lo1, 0.0f);
      float d2 = fmaxf(hi2 - lo2, 0.0f);
      float inter = (d0 * d1) * d2;
      float uni = (ivol + ls[6][jl]) - inter;
      float iou = inter / uni;  // IEEE div, matches reference semantics
      bits |= ((iou > NMS_IOU_F) && (j > i)) ? (1u << bit) : 0u;
    }
    wbits[wl] = bits;
  }
  uint4* mrow = (uint4*)(mask + ((size_t)(b * K_TOP + i)) * 64);
  mrow[jq * 4 + wv] = make_uint4(wbits[0], wbits[1], wbits[2], wbits[3]);
  U32* dgp = diag + (size_t)b * K_TOP;
  int g_src = i >> 5;
  U32* bc = bcnt + b * 64 + g_src;
  U64* bb = bkt + ((size_t)(b * 64 + g_src)) * CAPB;
#pragma unroll
  for (int wl = 0; wl < 4; ++wl) {
    int w = jq * 16 + wv * 4 + wl;
    if (w == (i >> 5)) dgp[i] = wbits[wl];  // exactly one (jq,wv,wl) per row
    if (wbits[wl]) {
      U32 p = atomicAdd(bc, 1u);
      if (p < (U32)CAPB)
        bb[p] = ((U64)((U32)((i & 31) << 6) | (U32)w) << 32) | wbits[wl];
    }
  }
}

// ---------------------------------------------------------------- edge-list greedy NMS + output
__global__ void __launch_bounds__(256) k_nms(const float* __restrict__ box,
                                             const U32* __restrict__ mask,
                                             const U32* __restrict__ diag,
                                             const U32* __restrict__ bcnt,
                                             const U64* __restrict__ bkt,
                                             float* __restrict__ out) {
  int b = blockIdx.x;
  int tid = threadIdx.x;
  int wv = tid >> 6, lane = tid & 63;
  const U32* mk = mask + (size_t)b * K_TOP * 64;
  const U32* dgp = diag + (size_t)b * K_TOP;
  const U32* bcg = bcnt + b * 64;
  const U64* bkg = bkt + (size_t)b * 64 * CAPB;

  __shared__ U64 lbkt[64 * CAPB];    // 32 KB
  __shared__ U32 ldiag[K_TOP];       // 8 KB
  __shared__ U32 lcnt[64];
  __shared__ U32 keepArr[64];

  // flat, fully-overlapped prologue copies — all loads in flight together
  for (int k = tid; k < K_TOP; k += 256) ldiag[k] = dgp[k];
  for (int k = tid; k < 64 * CAPB; k += 256) lbkt[k] = bkg[k];
  if (tid < 64) lcnt[tid] = bcg[tid];
  __syncthreads();

  if (wv == 0) {
    U32 keep = 0xFFFFFFFFu;  // lane l holds keep word l (j in [32l,32l+32))
    U32 cnt_l = lcnt[lane];
    bool ovf = (__ballot(cnt_l > (U32)CAPB) != 0ull);
    if (!ovf) {
      // -------- main path: O(E) --------
      for (int g = 0; g < 64; ++g) {
        U32 kw = (U32)__builtin_amdgcn_readlane((int)keep, g);
        if (!kw) continue;
        U32 dgl = ldiag[g * 32 + (lane & 31)];
        U32 nzw = (U32)__ballot(dgl != 0);   // low 32 = nonzero-diag bitmap
        U32 m = kw & nzw;
        while (m) {  // intra-block resolve: only rows with nonzero diag
          int q = __builtin_ctz(m);
          if ((kw >> q) & 1u)
            kw &= ~(U32)__builtin_amdgcn_readlane((int)dgl, q);
          m &= m - 1;
        }
        U32 n = (U32)__builtin_amdgcn_readlane((int)cnt_l, g);
        U32 acc = 0;
        for (U32 e0 = 0; e0 < n; e0 += 64) {
          U64 ev = lbkt[(U32)g * CAPB + e0 + (U32)lane];
          U32 evLo = (U32)ev, evHi = (U32)(ev >> 32);
          U32 lim = (n - e0 > 64u) ? 64u : (n - e0);
          for (U32 t = 0; t < lim; ++t) {
            U32 hi = (U32)__builtin_amdgcn_readlane((int)evHi, (int)t);
            U32 bt = (U32)__builtin_amdgcn_readlane((int)evLo, (int)t);
            U32 il = (hi >> 6) & 31u, w = hi & 63u;
            if ((kw >> il) & 1u)  // source row final-alive (uniform)
              acc |= (w == (U32)lane) ? bt : 0u;
          }
        }
        keep &= ~acc;  // lane g reproduces kw exactly (j>i diag argument)
      }
    } else {
      // -------- fallback: dense global (correct for any data) --------
      for (int g = 0; g < 64; ++g) {
        U32 kw = (U32)__builtin_amdgcn_readlane((int)keep, g);
        U32 dgl = ldiag[g * 32 + (lane & 31)];
#pragma unroll
        for (int q = 0; q < 32; ++q)
          if ((kw >> q) & 1u)
            kw &= ~(U32)__builtin_amdgcn_readlane((int)dgl, q);
        U32 rw[32];
#pragma unroll
        for (int q = 0; q < 32; ++q)
          rw[q] = mk[(size_t)(g * 32 + q) * 64 + lane];
        U32 acc = 0;
#pragma unroll
        for (int q = 0; q < 32; ++q) acc |= ((kw >> q) & 1u) ? rw[q] : 0u;
        keep &= ~acc;
      }
    }
    keepArr[lane] = keep;
  }
  __syncthreads();

  const float* B0 = box + (size_t)b * 14 * K_TOP;
  for (int t = tid; t < K_TOP; t += 256) {
    U32 kp = (keepArr[t >> 5] >> (t & 31)) & 1u;
    float sc = B0[13 * K_TOP + t];
    float vz = B0[0 * K_TOP + t], vy = B0[1 * K_TOP + t], vx = B0[2 * K_TOP + t];
    float dz = B0[3 * K_TOP + t], dy = B0[4 * K_TOP + t], dx = B0[5 * K_TOP + t];
    float* o = out + (size_t)(b * K_TOP + t) * 7;
    o[0] = kp ? sc : 0.0f;
    o[1] = kp ? vz : 0.0f;
    o[2] = kp ? vy : 0.0f;
    o[3] = kp ? vx : 0.0f;
    o[4] = kp ? dz : 0.0f;
    o[5] = kp ? dy : 0.0f;
    o[6] = kp ? dx : 0.0f;
  }
}

extern "C" void kernel_launch(void* const* d_in, const int* in_sizes, int n_in,
                              void* d_out, int out_size, void* d_ws, size_t ws_size,
                              hipStream_t stream) {
  const float* bboxes = (const float*)d_in[0];  // (2,6,64,96,96) f32
  const float* scores = (const float*)d_in[1];  // (2,64,96,96) f32
  float* out = (float*)d_out;                   // (2,2048,7) f32

  char* ws = (char*)d_ws;
  U32* hist = (U32*)(ws + OFF_HIST);
  U32* cnt  = (U32*)(ws + OFF_CNT);
  U64* cand = (U64*)(ws + OFF_CAND);
  float* box = (float*)(ws + OFF_BOX);
  U32* mask = (U32*)(ws + OFF_MASK);
  U32* diag = (U32*)(ws + OFF_DIAG);
  U32* bcnt = (U32*)(ws + OFF_BCNT);
  U64* bkt  = (U64*)(ws + OFF_BKT);

  k_zero<<<64, 256, 0, stream>>>(hist, cnt, bcnt);
  k_hist<<<dim3(72, NBATCH), 256, 0, stream>>>(scores, hist);
  k_collect<<<dim3(144, NBATCH), 256, 0, stream>>>(scores, hist, cnt, cand);
  k_cg<<<dim3(32, NBATCH), 256, 0, stream>>>(bboxes, cand, cnt, box);
  k_mask<<<dim3(128, NBATCH), 256, 0, stream>>>(box, mask, diag, bcnt, bkt);
  k_nms<<<NBATCH, 256, 0, stream>>>(box, mask, diag, bcnt, bkt, out);
}